// Round 1
// baseline (93.776 us; speedup 1.0000x reference)
//
#include <hip/hip_runtime.h>
#include <stdint.h>

#define N     6144
#define F     128
#define D     32
#define H     4
#define HID   128
#define NP1   6145

// ---- scratch layout (units: floats) ----
#define OFF_WH    0          // [N][128]
#define OFF_ES    786432     // [4][N]
#define OFF_ED    811008     // [4][N]
#define OFF_DS    835584     // [4][N]   sorted d values
#define OFF_PERM  860160     // [4][N]   permutation (int stored as float bits)
#define OFF_WHP   884736     // [4][32][N]  Wh permuted, transposed
#define OFF_PU1   1671168    // [4][NP1]
#define OFF_PV1   1695748    // [4][NP1]
#define OFF_PU2   1720352    // [4][NP1][32]  (padded to 32-float alignment)
#define OFF_PV2   2506912    // [4][NP1][32]
#define OFF_PART  3293472    // [4][24][32]
#define WS_FLOATS 3296544

__device__ float g_ws[WS_FLOATS];

// K1: Wh[n][h*32+d] = sum_f x[n][f] * W[h][f][d]; e_s/e_d via in-wave reduction.
__global__ __launch_bounds__(256) void k1_gemm(const float* __restrict__ x,
                                               const float* __restrict__ W,
                                               const float* __restrict__ a_src,
                                               const float* __restrict__ a_dst) {
    __shared__ float xs[2][F];
    int tid = threadIdx.x;
    int row = tid >> 7;          // 0..1
    int col = tid & 127;         // 0..127
    int n0  = blockIdx.x * 2;
    xs[row][col] = x[(n0 + row) * F + col];
    __syncthreads();
    int h = col >> 5;
    int d = col & 31;
    const float* Wp = W + h * (F * D) + d;     // stride D per f
    float acc = 0.f;
#pragma unroll 8
    for (int f = 0; f < F; ++f)
        acc = fmaf(xs[row][f], Wp[f * D], acc);
    int n = n0 + row;
    g_ws[OFF_WH + n * HID + col] = acc;
    // reduce over d within 32-lane groups
    float ts = acc * a_src[col];
    float td = acc * a_dst[col];
#pragma unroll
    for (int m = 1; m < 32; m <<= 1) {
        ts += __shfl_xor(ts, m);
        td += __shfl_xor(td, m);
    }
    if (d == 0) {
        g_ws[OFF_ES + h * N + n] = ts;
        g_ws[OFF_ED + h * N + n] = td;
    }
}

__device__ __forceinline__ uint32_t f2mono(float f) {
    uint32_t u = __float_as_uint(f);
    return (u & 0x80000000u) ? ~u : (u | 0x80000000u);
}

// K2: exact rank sort per head. 48 blocks/head, block = 1024 = 8 slices x 128 j.
__global__ __launch_bounds__(1024) void k2_rank() {
    __shared__ uint64_t keys[N];     // 48KB
    __shared__ int pcount[8][128];   // 4KB
    int b = blockIdx.x;              // 4*48
    int h = b / 48;
    int jbase = (b % 48) * 128;
    int tid = threadIdx.x;
    const float* ed = g_ws + OFF_ED + h * N;
    for (int r = tid; r < N; r += 1024)
        keys[r] = (((uint64_t)f2mono(ed[r])) << 13) | (uint32_t)r;
    __syncthreads();
    int s  = tid >> 7;       // same for all lanes of a wave -> LDS broadcast reads
    int jl = tid & 127;
    uint64_t myk = keys[jbase + jl];
    int cnt = 0;
    int beg = s * (N / 8), end = beg + (N / 8);
    for (int r = beg; r < end; ++r)
        cnt += (keys[r] < myk) ? 1 : 0;
    pcount[s][jl] = cnt;
    __syncthreads();
    if (tid < 128) {
        int rank = 0;
#pragma unroll
        for (int ss = 0; ss < 8; ++ss) rank += pcount[ss][tid];
        int jj = jbase + tid;
        g_ws[OFF_DS + h * N + rank]   = ed[jj];
        g_ws[OFF_PERM + h * N + rank] = __int_as_float(jj);
    }
}

// K2.5: WhP[h][d][r] = Wh[perm[h][r]][h*32+d]  (coalesced writes per d)
__global__ __launch_bounds__(256) void k25_gather() {
    int b = blockIdx.x;              // 4*24
    int h = b / 24;
    int r = (b % 24) * 256 + threadIdx.x;
    int p = __float_as_int(g_ws[OFF_PERM + h * N + r]);
    const float4* src = (const float4*)&g_ws[OFF_WH + p * HID + h * D];
    float v[32];
#pragma unroll
    for (int dg = 0; dg < 8; ++dg) {
        float4 t = src[dg];
        v[dg * 4 + 0] = t.x; v[dg * 4 + 1] = t.y;
        v[dg * 4 + 2] = t.z; v[dg * 4 + 3] = t.w;
    }
#pragma unroll
    for (int d = 0; d < 32; ++d)
        g_ws[OFF_WHP + (h * 32 + d) * N + r] = v[d];
}

// K3: 66 prefix scans per head. comp: 0=u scalar, 1=v scalar, 2..33=u*Wh[d], 34..65=v*Wh[d]
__global__ __launch_bounds__(256) void k3_scan() {
    __shared__ float tsum[256];
    int b = blockIdx.x;              // 4*66
    int h = b / 66;
    int comp = b % 66;
    int tid = threadIdx.x;
    int r0 = tid * 24;
    const float* dsp = g_ws + OFF_DS + h * N;

    float coef = (comp == 0 || (comp >= 2 && comp < 34)) ? 0.01f : 1.0f;
    int d = -1;
    if (comp >= 34) d = comp - 34;
    else if (comp >= 2) d = comp - 2;
    const float* wp = (d >= 0) ? (g_ws + OFF_WHP + (h * 32 + d) * N) : nullptr;

    float incl[24];
    float run = 0.f;
#pragma unroll
    for (int j = 0; j < 24; ++j) {
        float e = expf(coef * dsp[r0 + j]);
        float v = (d >= 0) ? e * wp[r0 + j] : e;
        run += v;
        incl[j] = run;
    }
    tsum[tid] = run;
    for (int off = 1; off < 256; off <<= 1) {
        __syncthreads();
        float t = (tid >= off) ? tsum[tid - off] : 0.f;
        __syncthreads();
        tsum[tid] += t;
    }
    float offset = tsum[tid] - run;   // exclusive offset for this thread

    float* out; int stride;
    if (comp == 0)       { out = g_ws + OFF_PU1 + h * NP1;                    stride = 1;  }
    else if (comp == 1)  { out = g_ws + OFF_PV1 + h * NP1;                    stride = 1;  }
    else if (comp < 34)  { out = g_ws + OFF_PU2 + (size_t)h * NP1 * 32 + d;   stride = 32; }
    else                 { out = g_ws + OFF_PV2 + (size_t)h * NP1 * 32 + d;   stride = 32; }
    if (tid == 0) out[0] = 0.f;
#pragma unroll
    for (int j = 0; j < 24; ++j)
        out[(size_t)(r0 + j + 1) * stride] = offset + incl[j];
}

// K4: per-row evaluation: binary search + 2 lookups; deterministic block reduction.
__global__ __launch_bounds__(256) void k4_eval() {
    __shared__ float ds[N];          // 24KB
    __shared__ float totv2[32];
    __shared__ float wred[4][32];
    __shared__ float totv1s;
    int b = blockIdx.x;              // 4*24
    int h = b / 24;
    int chunk = b % 24;
    int tid = threadIdx.x;
    const float* dsp = g_ws + OFF_DS + h * N;
    for (int r = tid; r < N; r += 256) ds[r] = dsp[r];
    if (tid < 32) totv2[tid] = g_ws[OFF_PV2 + ((size_t)h * NP1 + N) * 32 + tid];
    if (tid == 0) totv1s = g_ws[OFF_PV1 + h * NP1 + N];
    __syncthreads();

    int i = chunk * 256 + tid;
    float s = g_ws[OFF_ES + h * N + i];
    float nst = -s;
    int lo = 0, hi = N;
    while (lo < hi) { int mid = (lo + hi) >> 1; if (ds[mid] <= nst) lo = mid + 1; else hi = mid; }
    int k = lo;

    float e1 = expf(0.01f * s), e2 = expf(s);
    float pu1 = g_ws[OFF_PU1 + h * NP1 + k];
    float pv1 = g_ws[OFF_PV1 + h * NP1 + k];
    float denom = e1 * pu1 + e2 * (totv1s - pv1);
    float inv = 1.0f / denom;

    const float4* U = (const float4*)&g_ws[OFF_PU2 + ((size_t)h * NP1 + k) * 32];
    const float4* V = (const float4*)&g_ws[OFF_PV2 + ((size_t)h * NP1 + k) * 32];
    int lane = tid & 63, wid = tid >> 6;
#pragma unroll
    for (int dg = 0; dg < 8; ++dg) {
        float4 u4 = U[dg], v4 = V[dg];
        float us[4] = {u4.x, u4.y, u4.z, u4.w};
        float vs[4] = {v4.x, v4.y, v4.z, v4.w};
#pragma unroll
        for (int c = 0; c < 4; ++c) {
            int dd = dg * 4 + c;
            float num = e1 * us[c] + e2 * (totv2[dd] - vs[c]);
            float val = fmaxf(num, 0.f) * inv;   // relu(elu(x)) == relu(x); denom > 0
#pragma unroll
            for (int m = 1; m < 64; m <<= 1) val += __shfl_xor(val, m);
            if (lane == 0) wred[wid][dd] = val;
        }
    }
    __syncthreads();
    if (tid < 32) {
        float p = wred[0][tid] + wred[1][tid] + wred[2][tid] + wred[3][tid];
        g_ws[OFF_PART + (h * 24 + chunk) * 32 + tid] = p;
    }
}

// K5: y = h_mean @ W_fc + b_fc
__global__ __launch_bounds__(128) void k5_out(const float* __restrict__ W_fc,
                                              const float* __restrict__ b_fc,
                                              float* __restrict__ out) {
    __shared__ float hm[128];
    int tid = threadIdx.x;
    {
        int hh = tid >> 5, dd = tid & 31;
        float sum = 0.f;
        for (int ch = 0; ch < 24; ++ch)
            sum += g_ws[OFF_PART + (hh * 24 + ch) * 32 + dd];
        hm[tid] = sum * (1.0f / (float)N);
    }
    __syncthreads();
    float y = b_fc[tid];
#pragma unroll 8
    for (int c = 0; c < 128; ++c)
        y = fmaf(hm[c], W_fc[c * 128 + tid], y);
    out[tid] = y;
}

extern "C" void kernel_launch(void* const* d_in, const int* in_sizes, int n_in,
                              void* d_out, int out_size, void* d_ws, size_t ws_size,
                              hipStream_t stream) {
    (void)in_sizes; (void)n_in; (void)d_ws; (void)ws_size; (void)out_size;
    const float* x     = (const float*)d_in[0];
    const float* W     = (const float*)d_in[1];
    const float* a_src = (const float*)d_in[2];
    const float* a_dst = (const float*)d_in[3];
    const float* W_fc  = (const float*)d_in[4];
    const float* b_fc  = (const float*)d_in[5];
    float* out = (float*)d_out;

    k1_gemm<<<dim3(N / 2), dim3(256), 0, stream>>>(x, W, a_src, a_dst);
    k2_rank<<<dim3(H * 48), dim3(1024), 0, stream>>>();
    k25_gather<<<dim3(H * 24), dim3(256), 0, stream>>>();
    k3_scan<<<dim3(H * 66), dim3(256), 0, stream>>>();
    k4_eval<<<dim3(H * 24), dim3(256), 0, stream>>>();
    k5_out<<<dim3(1), dim3(128), 0, stream>>>(W_fc, b_fc, out);
}

// Round 2
// 92.713 us; speedup vs baseline: 1.0115x; 1.0115x over previous
//
#include <hip/hip_runtime.h>
#include <stdint.h>

#define N     6144
#define F     128
#define D     32
#define H     4
#define HID   128
#define NP1   6145
#define NCHUNK 24
#define CS    256

// ---- scratch layout (units: floats) ----
#define OFF_WH    0          // [N][128]
#define OFF_ES    786432     // [4][N]
#define OFF_ED    811008     // [4][N]
#define OFF_DS    835584     // [4][N]   sorted d values
#define OFF_PERM  860160     // [4][N]   permutation (int bits)
#define OFF_WHP   884736     // [4][32][N]  Wh permuted, transposed
#define OFF_PU    1671168    // [4][33][NP1]  row0=scalar u-scan, rows 1..32 = u*wh[d]
#define OFF_PV    2482308    // [4][33][NP1]  same for v
#define OFF_PART  3293448    // [4][24][32]
#define WS_FLOATS 3296520

__device__ float    g_ws[WS_FLOATS];
__device__ uint64_t g_keys[H * N];   // sorted 256-key chunks

// ------------------------------------------------------------------
// K1: Wh = x @ W (per-head), e_s/e_d reductions.
// 4-row register blocking; x read via wave-uniform scalar loads.
__global__ __launch_bounds__(256) void k1_gemm(const float* __restrict__ x,
                                               const float* __restrict__ W,
                                               const float* __restrict__ a_src,
                                               const float* __restrict__ a_dst) {
    int tid  = threadIdx.x;
    int wid  = tid >> 6;
    int lane = tid & 63;
    int rg   = wid & 1;            // row group within block
    int ch   = wid >> 1;           // column half
    int row0 = __builtin_amdgcn_readfirstlane(blockIdx.x * 8 + rg * 4);
    int col  = ch * 64 + lane;     // 0..127
    int h    = col >> 5;
    const float* __restrict__ xr = x + (size_t)row0 * F;
    const float* __restrict__ Wp = W + h * (F * D) + (col & 31);
    float acc[4] = {0.f, 0.f, 0.f, 0.f};
#pragma unroll 4
    for (int f = 0; f < F; ++f) {
        float w  = Wp[f * D];
        float x0 = xr[f];
        float x1 = xr[F + f];
        float x2 = xr[2 * F + f];
        float x3 = xr[3 * F + f];
        acc[0] = fmaf(x0, w, acc[0]);
        acc[1] = fmaf(x1, w, acc[1]);
        acc[2] = fmaf(x2, w, acc[2]);
        acc[3] = fmaf(x3, w, acc[3]);
    }
    float as = a_src[col], ad = a_dst[col];
#pragma unroll
    for (int r = 0; r < 4; ++r) {
        int n = row0 + r;
        g_ws[OFF_WH + (size_t)n * HID + col] = acc[r];
        float ts = acc[r] * as;
        float td = acc[r] * ad;
#pragma unroll
        for (int m = 1; m < 32; m <<= 1) {
            ts += __shfl_xor(ts, m);
            td += __shfl_xor(td, m);
        }
        if ((lane & 31) == 0) {
            g_ws[OFF_ES + h * N + n] = ts;
            g_ws[OFF_ED + h * N + n] = td;
        }
    }
}

__device__ __forceinline__ uint32_t f2mono(float f) {
    uint32_t u = __float_as_uint(f);
    return (u & 0x80000000u) ? ~u : (u | 0x80000000u);
}

// K2a: sort each 256-key chunk via all-pairs rank (LDS broadcast reads).
__global__ __launch_bounds__(256) void k2a_chunksort() {
    __shared__ uint64_t keys[CS];
    int b = blockIdx.x;            // H*NCHUNK
    int h = b / NCHUNK;
    int c = b % NCHUNK;
    int tid = threadIdx.x;
    int j = c * CS + tid;
    float dv = g_ws[OFF_ED + h * N + j];
    uint64_t myk = (((uint64_t)f2mono(dv)) << 13) | (uint32_t)j;
    keys[tid] = myk;
    __syncthreads();
    int rank = 0;
    for (int s = 0; s < CS; ++s)
        rank += (keys[s] < myk) ? 1 : 0;
    g_keys[(h * NCHUNK + c) * CS + rank] = myk;
}

// K2b: global rank = in-chunk rank + binary searches over other sorted chunks.
__global__ __launch_bounds__(256) void k2b_rank() {
    __shared__ uint64_t ks[N];     // 48 KB
    int b = blockIdx.x;            // H*NCHUNK
    int h = b / NCHUNK;
    int c = b % NCHUNK;
    int tid = threadIdx.x;
    const uint64_t* kh = g_keys + (size_t)h * N;
    for (int r = tid; r < N; r += 256) ks[r] = kh[r];
    __syncthreads();
    uint64_t myk = ks[c * CS + tid];
    int rank = tid;                // within own (sorted) chunk
    for (int cc = 0; cc < NCHUNK; ++cc) {
        if (cc == c) continue;
        int base = cc * CS;
        int pos = 0;
#pragma unroll
        for (int step = 256; step >= 1; step >>= 1) {
            int np = pos + step;
            if (np <= CS && ks[base + np - 1] < myk) pos = np;
        }
        rank += pos;
    }
    uint32_t m = (uint32_t)(myk >> 13);
    uint32_t u = (m & 0x80000000u) ? (m ^ 0x80000000u) : ~m;
    int idx = (int)(myk & 8191u);
    g_ws[OFF_DS + h * N + rank]   = __uint_as_float(u);
    g_ws[OFF_PERM + h * N + rank] = __int_as_float(idx);
}

// K2.5: WhP[h][d][r] = Wh[perm[h][r]][h*32+d]  (coalesced writes per d)
__global__ __launch_bounds__(256) void k25_gather() {
    int b = blockIdx.x;              // 4*24
    int h = b / 24;
    int r = (b % 24) * 256 + threadIdx.x;
    int p = __float_as_int(g_ws[OFF_PERM + h * N + r]);
    const float4* src = (const float4*)&g_ws[OFF_WH + (size_t)p * HID + h * D];
    float v[32];
#pragma unroll
    for (int dg = 0; dg < 8; ++dg) {
        float4 t = src[dg];
        v[dg * 4 + 0] = t.x; v[dg * 4 + 1] = t.y;
        v[dg * 4 + 2] = t.z; v[dg * 4 + 3] = t.w;
    }
#pragma unroll
    for (int d = 0; d < 32; ++d)
        g_ws[OFF_WHP + (size_t)(h * 32 + d) * N + r] = v[d];
}

// K3: 66 scans per head into column-major [h][33][NP1] (dense writes).
// comp<33 -> u-family (coef .01), row=comp; else v-family, row=comp-33.
// row 0 = scalar exp; rows 1..32 = exp * wh[row-1].
__global__ __launch_bounds__(256) void k3_scan() {
    __shared__ float tsum[256];
    int b = blockIdx.x;              // 4*66
    int h = b / 66;
    int comp = b % 66;
    int tid = threadIdx.x;
    int r0 = tid * 24;
    const float* dsp = g_ws + OFF_DS + h * N;
    bool isU = comp < 33;
    float coef = isU ? 0.01f : 1.0f;
    int row = isU ? comp : comp - 33;    // 0..32
    const float* wp = (row > 0) ? (g_ws + OFF_WHP + (size_t)(h * 32 + row - 1) * N) : nullptr;

    float incl[24];
    float run = 0.f;
#pragma unroll
    for (int j = 0; j < 24; ++j) {
        float e = expf(coef * dsp[r0 + j]);
        float v = (row > 0) ? e * wp[r0 + j] : e;
        run += v;
        incl[j] = run;
    }
    tsum[tid] = run;
    for (int off = 1; off < 256; off <<= 1) {
        __syncthreads();
        float t = (tid >= off) ? tsum[tid - off] : 0.f;
        __syncthreads();
        tsum[tid] += t;
    }
    float offset = tsum[tid] - run;

    float* out = g_ws + (isU ? OFF_PU : OFF_PV) + ((size_t)h * 33 + row) * NP1;
    if (tid == 0) out[0] = 0.f;
#pragma unroll
    for (int j = 0; j < 24; ++j)
        out[r0 + j + 1] = offset + incl[j];
}

// K4: binary search + per-d column gathers + deterministic reduction.
__global__ __launch_bounds__(256) void k4_eval() {
    __shared__ float ds[N];          // 24KB
    __shared__ float totv2[32];
    __shared__ float wred[4][32];
    int b = blockIdx.x;              // 4*24
    int h = b / 24;
    int chunk = b % 24;
    int tid = threadIdx.x;
    const float* dsp = g_ws + OFF_DS + h * N;
    for (int r = tid; r < N; r += 256) ds[r] = dsp[r];
    if (tid < 32)
        totv2[tid] = g_ws[OFF_PV + ((size_t)h * 33 + 1 + tid) * NP1 + N];
    __syncthreads();
    float totv1 = g_ws[OFF_PV + (size_t)h * 33 * NP1 + N];

    int i = chunk * 256 + tid;
    float s = g_ws[OFF_ES + h * N + i];
    float nst = -s;
    int k = 0;
#pragma unroll
    for (int step = 4096; step >= 1; step >>= 1) {
        int np = k + step;
        if (np <= N && ds[np - 1] <= nst) k = np;
    }

    float e1 = expf(0.01f * s), e2 = expf(s);
    float pu1 = g_ws[OFF_PU + (size_t)h * 33 * NP1 + k];
    float pv1 = g_ws[OFF_PV + (size_t)h * 33 * NP1 + k];
    float denom = e1 * pu1 + e2 * (totv1 - pv1);
    float inv = 1.0f / denom;

    const float* pub = g_ws + OFF_PU + ((size_t)h * 33 + 1) * NP1 + k;
    const float* pvb = g_ws + OFF_PV + ((size_t)h * 33 + 1) * NP1 + k;
    int lane = tid & 63, wid = tid >> 6;
#pragma unroll
    for (int dd = 0; dd < 32; ++dd) {
        float uu = pub[(size_t)dd * NP1];
        float vv = pvb[(size_t)dd * NP1];
        float num = e1 * uu + e2 * (totv2[dd] - vv);
        float val = fmaxf(num, 0.f) * inv;   // relu(elu(x)) == relu(x); denom > 0
#pragma unroll
        for (int m = 1; m < 64; m <<= 1) val += __shfl_xor(val, m);
        if (lane == 0) wred[wid][dd] = val;
    }
    __syncthreads();
    if (tid < 32) {
        float p = wred[0][tid] + wred[1][tid] + wred[2][tid] + wred[3][tid];
        g_ws[OFF_PART + (h * 24 + chunk) * 32 + tid] = p;
    }
}

// K5: y = h_mean @ W_fc + b_fc
__global__ __launch_bounds__(128) void k5_out(const float* __restrict__ W_fc,
                                              const float* __restrict__ b_fc,
                                              float* __restrict__ out) {
    __shared__ float hm[128];
    int tid = threadIdx.x;
    {
        int hh = tid >> 5, dd = tid & 31;
        float sum = 0.f;
        for (int ch = 0; ch < 24; ++ch)
            sum += g_ws[OFF_PART + (hh * 24 + ch) * 32 + dd];
        hm[tid] = sum * (1.0f / (float)N);
    }
    __syncthreads();
    float y = b_fc[tid];
#pragma unroll 8
    for (int c = 0; c < 128; ++c)
        y = fmaf(hm[c], W_fc[c * 128 + tid], y);
    out[tid] = y;
}

extern "C" void kernel_launch(void* const* d_in, const int* in_sizes, int n_in,
                              void* d_out, int out_size, void* d_ws, size_t ws_size,
                              hipStream_t stream) {
    (void)in_sizes; (void)n_in; (void)d_ws; (void)ws_size; (void)out_size;
    const float* x     = (const float*)d_in[0];
    const float* W     = (const float*)d_in[1];
    const float* a_src = (const float*)d_in[2];
    const float* a_dst = (const float*)d_in[3];
    const float* W_fc  = (const float*)d_in[4];
    const float* b_fc  = (const float*)d_in[5];
    float* out = (float*)d_out;

    k1_gemm<<<dim3(N / 8), dim3(256), 0, stream>>>(x, W, a_src, a_dst);
    k2a_chunksort<<<dim3(H * NCHUNK), dim3(256), 0, stream>>>();
    k2b_rank<<<dim3(H * NCHUNK), dim3(256), 0, stream>>>();
    k25_gather<<<dim3(H * 24), dim3(256), 0, stream>>>();
    k3_scan<<<dim3(H * 66), dim3(256), 0, stream>>>();
    k4_eval<<<dim3(H * 24), dim3(256), 0, stream>>>();
    k5_out<<<dim3(1), dim3(128), 0, stream>>>(W_fc, b_fc, out);
}